// Round 5
// baseline (387.898 us; speedup 1.0000x reference)
//
#include <hip/hip_runtime.h>

typedef unsigned short ushort_t;
typedef __attribute__((ext_vector_type(8))) short s16x8;   // 8 bf16 (4 VGPRs) MFMA A/B frag
typedef __attribute__((ext_vector_type(4))) float f32x4;   // 4 f32 MFMA C/D frag

#define B_PATHS 8192
#define NSTEP   30
#define DD      100
#define TT      29            // number of subnets
#define ROWSTR  3000          // NSTEP*DD floats per path
#define LDK     136           // padded k-stride (bf16 elems) for act tiles
#define WFRAGSZ 14336         // per-stage frag-ordered W: 4 kb * 7 nt * 64 lanes * 8 elems
#define NCHUNK  8             // t-chunks of 4 (last has 1)
#define CHSZ    4
#define DT_C    (1.0f/30.0f)
#define R_C     0.05f
#define GFAC    (1.0f + R_C*DT_C)
#define EPS_C   1e-3f

__device__ __forceinline__ ushort_t f2bf(float f) {  // RNE f32->bf16
  unsigned u = __float_as_uint(f);
  u = u + 0x7FFFu + ((u >> 16) & 1u);
  return (ushort_t)(u >> 16);
}
__device__ __forceinline__ float bf2f(ushort_t u) {
  return __uint_as_float(((unsigned)u) << 16);
}

// ---------------------------------------------------------------------------
// Prep: fold BN into weights/biases; emit W in MFMA B-fragment order:
//   elem j of chunk c=((kb*7+nt)*64+lane):  B[n=nt*16+(lane&15)][k=kb*32+(lane>>4)*8+j]
// ---------------------------------------------------------------------------
__global__ void prep_kernel(const float* __restrict__ W1, const float* __restrict__ W2,
                            const float* __restrict__ W3,
                            const float* g0, const float* b0, const float* m0, const float* v0,
                            const float* g1, const float* b1, const float* m1, const float* v1,
                            const float* g2, const float* b2, const float* m2, const float* v2,
                            const float* g3, const float* b3, const float* m3, const float* v3,
                            ushort_t* __restrict__ wprep, float* __restrict__ bprep)
{
  const int mat = blockIdx.x, t = blockIdx.y, tid = threadIdx.x;
  __shared__ float wsh[110*110];
  __shared__ float sin_[112], hin_[112], sout_[112], hout_[112];

  int Kr, Nr; const float* W; const float *g, *bb, *mm, *vv;
  if (mat == 0)      { Kr = 100; Nr = 110; W = W1 + t*11000; g = g0+t*100; bb = b0+t*100; mm = m0+t*100; vv = v0+t*100; }
  else if (mat == 1) { Kr = 110; Nr = 110; W = W2 + t*12100; g = g1+t*110; bb = b1+t*110; mm = m1+t*110; vv = v1+t*110; }
  else               { Kr = 110; Nr = 100; W = W3 + t*11000; g = g2+t*110; bb = b2+t*110; mm = m2+t*110; vv = v2+t*110; }

  if (tid < Kr) {
    float s = g[tid] * rsqrtf(vv[tid] + EPS_C);
    sin_[tid] = s; hin_[tid] = bb[tid] - mm[tid]*s;
  }
  if (mat == 2 && tid < Nr) {
    float s = g3[t*100+tid] * rsqrtf(v3[t*100+tid] + EPS_C);
    sout_[tid] = s; hout_[tid] = b3[t*100+tid] - m3[t*100+tid]*s;
  }
  for (int i = tid; i < Kr*Nr; i += 256) wsh[i] = W[i];
  __syncthreads();

  if (tid < 128) {
    float c = 0.f;
    if (tid < Nr) {
      for (int k = 0; k < Kr; ++k) c += hin_[k] * wsh[k*Nr + tid];
      if (mat == 2) c = c * sout_[tid] + hout_[tid];
    }
    bprep[(t*3 + mat)*128 + tid] = c;
  }

  ushort_t* wo = wprep + (size_t)(t*3 + mat) * WFRAGSZ;
  for (int ch = tid; ch < 1792; ch += 256) {            // 1792 chunks of 8 elems
    const int lane = ch & 63, ntkb = ch >> 6;
    const int nt = ntkb % 7, kb = ntkb / 7;
    const int n  = nt*16 + (lane & 15);
    const int k0 = kb*32 + (lane >> 4)*8;
    ushort_t tmp[8];
#pragma unroll
    for (int j = 0; j < 8; ++j) {
      const int k = k0 + j;
      float v = 0.f;
      if (n < Nr && k < Kr) {
        v = sin_[k] * wsh[k*Nr + n];
        if (mat == 2) v *= sout_[n];
      }
      tmp[j] = f2bf(v);
    }
    ushort4 lo; lo.x = tmp[0]; lo.y = tmp[1]; lo.z = tmp[2]; lo.w = tmp[3];
    ushort4 hi; hi.x = tmp[4]; hi.y = tmp[5]; hi.z = tmp[6]; hi.w = tmp[7];
    *(ushort4*)(wo + ch*8)     = lo;
    *(ushort4*)(wo + ch*8 + 4) = hi;
  }
}

// ---------------------------------------------------------------------------
// One MLP stage, M=32 rows per wave. In-place (actIn==actOut) is safe: all
// ds_reads (a-frags) are preloaded before the MFMA loop; same-wave DS ops are
// in-order; clobbers pin compiler ordering. (Pattern validated in R4.)
// ---------------------------------------------------------------------------
__device__ __forceinline__ void mlp_stage32(const ushort_t* actIn, ushort_t* actOut,
                                            const ushort_t* __restrict__ wfrag,
                                            const float* __restrict__ biasg,
                                            int lane, int lrow, int quad, bool relu)
{
  s16x8 aL[4], aH[4];
#pragma unroll
  for (int kb = 0; kb < 4; ++kb) {
    aL[kb] = *(const s16x8*)(actIn + lrow*LDK + kb*32 + quad*8);
    aH[kb] = *(const s16x8*)(actIn + (16 + lrow)*LDK + kb*32 + quad*8);
  }
  f32x4 accL[7], accH[7];
  const f32x4 z4 = {0.f, 0.f, 0.f, 0.f};
#pragma unroll
  for (int nt = 0; nt < 7; ++nt) { accL[nt] = z4; accH[nt] = z4; }
#pragma unroll
  for (int kb = 0; kb < 4; ++kb) {
#pragma unroll
    for (int nt = 0; nt < 7; ++nt) {
      s16x8 b = *(const s16x8*)(wfrag + ((kb*7 + nt)*64 + lane)*8);
      accL[nt] = __builtin_amdgcn_mfma_f32_16x16x32_bf16(aL[kb], b, accL[nt], 0, 0, 0);
      accH[nt] = __builtin_amdgcn_mfma_f32_16x16x32_bf16(aH[kb], b, accH[nt], 0, 0, 0);
    }
  }
  __asm__ volatile("" ::: "memory");
#pragma unroll
  for (int nt = 0; nt < 7; ++nt) {
    const int col = nt*16 + lrow;
    const float bv = biasg[col];
#pragma unroll
    for (int r = 0; r < 4; ++r) {
      float uL = accL[nt][r] + bv;           // C/D: row=quad*4+r, col=lane&15
      float uH = accH[nt][r] + bv;
      if (relu) { uL = uL > 0.f ? uL : 0.f; uH = uH > 0.f ? uH : 0.f; }
      actOut[(quad*4 + r)*LDK + col]      = f2bf(uL);
      actOut[(16 + quad*4 + r)*LDK + col] = f2bf(uH);
    }
  }
#pragma unroll
  for (int r = 0; r < 4; ++r) {              // zero pad cols [112,128)
    actOut[(quad*4 + r)*LDK + 112 + lrow]      = 0;
    actOut[(16 + quad*4 + r)*LDK + 112 + lrow] = 0;
  }
  __asm__ volatile("" ::: "memory");
}

// ---------------------------------------------------------------------------
// Streaming subnet: block = (path-tile of 64, t-chunk). Each wave handles 32
// paths through the chunk's t-loop. X/DW reads are contiguous multi-KB
// streams per path; weights (2.5 MB total) are L2-resident. Per-chunk output:
// P[b] = sum_{t in chunk} g^(28-t) * s_{t+1}[b].
// ---------------------------------------------------------------------------
__global__ __launch_bounds__(128, 2)
void subnet_kernel(const float* __restrict__ X, const float* __restrict__ DW,
                   const float* __restrict__ sigmas,
                   const ushort_t* __restrict__ wprep, const float* __restrict__ bprep,
                   float* __restrict__ pbuf)
{
  __shared__ __align__(16) ushort_t actA[2][32*LDK];   // staged X (kept through stages)
  __shared__ __align__(16) ushort_t actB[2][32*LDK];   // h1 -> h2 -> Z (in-place)

  const int tid  = threadIdx.x;
  const int wv   = tid >> 6;
  const int lane = tid & 63, lrow = lane & 15, quad = lane >> 4;
  const int row2 = lane >> 1, part2 = lane & 1;        // 2 lanes per path row
  const int m0   = blockIdx.x * 64 + wv * 32;
  const int brow = m0 + row2;
  const int c    = blockIdx.y;
  const int t0   = c * CHSZ, t1 = (t0 + CHSZ < TT) ? t0 + CHSZ : TT;

  ushort_t* A = actA[wv];
  ushort_t* B = actB[wv];

  // zero A pad cols [100,128) once (groups 25..31); staging rewrites only <25
#pragma unroll
  for (int g = part2; g < 7; g += 2) {
    ushort4 z; z.x = 0; z.y = 0; z.z = 0; z.w = 0;
    *(ushort4*)(A + row2*LDK + (25 + g)*4) = z;
  }
  __asm__ volatile("" ::: "memory");

  float P = 0.f;

  for (int t = t0; t < t1; ++t) {
    // ---- stage X[brow, t+1, :] -> bf16 A ; prefetch DW[brow, t+1, :] -> regs
    const float* xr = X  + (size_t)brow*ROWSTR + (t+1)*DD;
    const float* dr = DW + (size_t)brow*ROWSTR + (t+1)*DD;
    float4 dwv[13];
#pragma unroll
    for (int g = 0; g < 13; ++g) {
      const int cgrp = part2*13 + g;
      const int cc   = cgrp < 25 ? cgrp : 24;          // clamp keeps loads uniform
      const float4 xv = *(const float4*)(xr + cc*4);
      dwv[g] = *(const float4*)(dr + cc*4);
      if (cgrp < 25) {
        ushort4 u;
        u.x = f2bf(xv.x); u.y = f2bf(xv.y); u.z = f2bf(xv.z); u.w = f2bf(xv.w);
        *(ushort4*)(A + row2*LDK + cgrp*4) = u;
      }
    }
    __asm__ volatile("" ::: "memory");

    const ushort_t* wf = wprep + (size_t)(t*3) * WFRAGSZ;
    const float*    bg = bprep + (t*3) * 128;

    mlp_stage32(A, B, wf,             bg,       lane, lrow, quad, true);
    mlp_stage32(B, B, wf + WFRAGSZ,   bg + 128, lane, lrow, quad, true);
    mlp_stage32(B, B, wf + 2*WFRAGSZ, bg + 256, lane, lrow, quad, false); // Z (bn3 folded)

    // ---- epilogue: s_{t+1}[brow] = sum_d sigma_d * X[brow,xt,d] * Z[d] * DW[brow,t+1,d]
    float p = 0.f;
    if (t < TT - 1) {                                  // xt = t+1 == staged row (bf16 in A)
#pragma unroll
      for (int g = 0; g < 13; ++g) {
        const int cgrp = part2*13 + g;
        if (cgrp < 25) {
          const float4 sg = *(const float4*)(sigmas + cgrp*4);
          const ushort4 xu = *(const ushort4*)(A + row2*LDK + cgrp*4);
          const ushort4 zu = *(const ushort4*)(B + row2*LDK + cgrp*4);
          p += sg.x*bf2f(xu.x)*dwv[g].x*bf2f(zu.x);
          p += sg.y*bf2f(xu.y)*dwv[g].y*bf2f(zu.y);
          p += sg.z*bf2f(xu.z)*dwv[g].z*bf2f(zu.z);
          p += sg.w*bf2f(xu.w)*dwv[g].w*bf2f(zu.w);
        }
      }
    } else {                                           // t==28: xt = 28 (f32 from global, L2-hot)
      const float* xe = X + (size_t)brow*ROWSTR + 28*DD;
#pragma unroll
      for (int g = 0; g < 13; ++g) {
        const int cgrp = part2*13 + g;
        if (cgrp < 25) {
          const float4 sg = *(const float4*)(sigmas + cgrp*4);
          const float4 xv = *(const float4*)(xe + cgrp*4);
          const ushort4 zu = *(const ushort4*)(B + row2*LDK + cgrp*4);
          p += sg.x*xv.x*dwv[g].x*bf2f(zu.x);
          p += sg.y*xv.y*dwv[g].y*bf2f(zu.y);
          p += sg.z*xv.z*dwv[g].z*bf2f(zu.z);
          p += sg.w*xv.w*dwv[g].w*bf2f(zu.w);
        }
      }
    }
    p += __shfl_xor(p, 1, 64);                         // combine the 2 lanes of this row

    float w = 1.f;                                     // g^(28-t), wave-uniform tiny loop
    for (int k = 0; k < 28 - t; ++k) w *= GFAC;
    P += w * p;
    __asm__ volatile("" ::: "memory");                 // epilogue reads before next staging writes
  }

  if (part2 == 0)
    pbuf[(size_t)c*B_PATHS + brow] = P;
}

// ---------------------------------------------------------------------------
// Final: y = g^30*y0 + g^29*s0 + sum_c P_c ;  s0 from z_init.
// ---------------------------------------------------------------------------
__global__ void y_kernel(const float* __restrict__ X, const float* __restrict__ DW,
                         const float* __restrict__ sigmas, const float* __restrict__ y_init,
                         const float* __restrict__ z_init, const float* __restrict__ pbuf,
                         float* __restrict__ out)
{
  const int b = blockIdx.x * blockDim.x + threadIdx.x;
  const float* xr = X + (size_t)b * ROWSTR;   // step 0
  const float* dr = DW + (size_t)b * ROWSTR;
  float s0 = 0.f;
#pragma unroll 5
  for (int c = 0; c < 25; ++c) {
    float4 xv = *(const float4*)(xr + c*4);
    float4 dv = *(const float4*)(dr + c*4);
    float4 sg = *(const float4*)(sigmas + c*4);
    float4 zv = *(const float4*)(z_init + c*4);
    s0 += sg.x*xv.x*zv.x*dv.x;
    s0 += sg.y*xv.y*zv.y*dv.y;
    s0 += sg.z*xv.z*zv.z*dv.z;
    s0 += sg.w*xv.w*zv.w*dv.w;
  }
  float acc = 0.f;
#pragma unroll
  for (int c = 0; c < NCHUNK; ++c) acc += pbuf[(size_t)c*B_PATHS + b];

  float y = y_init[0]*GFAC + s0;              // g*y0 + s0
#pragma unroll
  for (int k = 0; k < 29; ++k) y *= GFAC;     // -> g^30*y0 + g^29*s0
  out[b] = y + acc;
}

extern "C" void kernel_launch(void* const* d_in, const int* in_sizes, int n_in,
                              void* d_out, int out_size, void* d_ws, size_t ws_size,
                              hipStream_t stream) {
  const float* X      = (const float*)d_in[0];
  const float* DWs    = (const float*)d_in[1];
  const float* sigmas = (const float*)d_in[2];
  const float* y_init = (const float*)d_in[3];
  const float* z_init = (const float*)d_in[4];
  const float* W1     = (const float*)d_in[5];
  const float* W2     = (const float*)d_in[6];
  const float* W3     = (const float*)d_in[7];
  const float* bn[16];
  for (int i = 0; i < 16; ++i) bn[i] = (const float*)d_in[8 + i];

  char* ws = (char*)d_ws;
  ushort_t* wprep = (ushort_t*)ws;                     // 87*14336*2 = 2,494,464 B
  float*    bprep = (float*)(ws + 2494464);            // 87*128*4   =    44,544 B
  float*    pbuf  = (float*)(ws + 2539008);            // 8*8192*4   =   262,144 B
  float*    out   = (float*)d_out;

  prep_kernel<<<dim3(3, TT), 256, 0, stream>>>(
      W1, W2, W3,
      bn[0], bn[1], bn[2], bn[3],  bn[4], bn[5], bn[6], bn[7],
      bn[8], bn[9], bn[10], bn[11], bn[12], bn[13], bn[14], bn[15],
      wprep, bprep);
  subnet_kernel<<<dim3(B_PATHS/64, NCHUNK), 128, 0, stream>>>(
      X, DWs, sigmas, wprep, bprep, pbuf);
  y_kernel<<<dim3(B_PATHS/256), 256, 0, stream>>>(
      X, DWs, sigmas, y_init, z_init, pbuf, out);
}